// Round 7
// baseline (707.242 us; speedup 1.0000x reference)
//
#include <hip/hip_runtime.h>
#include <hip/hip_fp16.h>

#define BLOCK 256
#define PAD 16   // one counter per 64B cache line

// ---------------- typed vector load/store helpers ----------------
__device__ inline float4 ld4f(const float* p) { return *(const float4*)p; }
__device__ inline float4 ld4f(const __half* p) {
    uint2 u = *(const uint2*)p;
    __half2 a = *reinterpret_cast<__half2*>(&u.x);
    __half2 b = *reinterpret_cast<__half2*>(&u.y);
    float2 fa = __half22float2(a), fb = __half22float2(b);
    return make_float4(fa.x, fa.y, fb.x, fb.y);
}
__device__ inline void st4f(float* p, float4 v) { *(float4*)p = v; }
__device__ inline void st4f(__half* p, float4 v) {
    __half2 a = __floats2half2_rn(v.x, v.y);
    __half2 b = __floats2half2_rn(v.z, v.w);
    uint2 u;
    u.x = *reinterpret_cast<unsigned*>(&a);
    u.y = *reinterpret_cast<unsigned*>(&b);
    *(uint2*)p = u;
}
__device__ inline void st8f(float* p, const float f[8]) {
    *(float4*)p       = make_float4(f[0], f[1], f[2], f[3]);
    *(float4*)(p + 4) = make_float4(f[4], f[5], f[6], f[7]);
}
__device__ inline void st8f(__half* p, const float f[8]) {
    union { __half2 h[4]; float4 v; } u;
    u.h[0] = __floats2half2_rn(f[0], f[1]);
    u.h[1] = __floats2half2_rn(f[2], f[3]);
    u.h[2] = __floats2half2_rn(f[4], f[5]);
    u.h[3] = __floats2half2_rn(f[6], f[7]);
    *(float4*)p = u.v;
}
__device__ inline void ld2v(const float* p, float* f) {
    float2 v = *(const float2*)p; f[0] = v.x; f[1] = v.y;
}
__device__ inline void ld2v(const __half* p, float* f) {
    float2 v = __half22float2(*(const __half2*)p); f[0] = v.x; f[1] = v.y;
}
__device__ inline void ld8v(const float* p, float* f) {
    float4 a = *(const float4*)p, b = *(const float4*)(p + 4);
    f[0]=a.x; f[1]=a.y; f[2]=a.z; f[3]=a.w; f[4]=b.x; f[5]=b.y; f[6]=b.z; f[7]=b.w;
}
__device__ inline void ld8v(const __half* p, float* f) {
    float4 r = *(const float4*)p;
    const __half2* h = (const __half2*)&r;
#pragma unroll
    for (int j = 0; j < 4; ++j) {
        float2 fj = __half22float2(h[j]);
        f[2*j] = fj.x; f[2*j+1] = fj.y;
    }
}

// ---------------- degree (padded counters, int atomics) ----------------
__global__ void deg_kernel(const int* __restrict__ src, const int* __restrict__ dst,
                           int* __restrict__ degOpad, int* __restrict__ degIpad, int E) {
    int e = blockIdx.x * blockDim.x + threadIdx.x;
    if (e < E) {
        atomicAdd(&degOpad[src[e] * PAD], 1);
        atomicAdd(&degIpad[dst[e] * PAD], 1);
    }
}

// ---------------- hierarchical exclusive scan of degI (padded input) ----------------
__global__ void scan_local(const int* __restrict__ degIpad, int* __restrict__ rowStart,
                           int* __restrict__ blockSums, int N) {
    __shared__ int tmp[1024];
    int tid = threadIdx.x;
    int i = blockIdx.x * 1024 + tid;
    int v = (i < N) ? degIpad[i * PAD] : 0;
    tmp[tid] = v;
    __syncthreads();
    for (int off = 1; off < 1024; off <<= 1) {
        int t = (tid >= off) ? tmp[tid - off] : 0;
        __syncthreads();
        tmp[tid] += t;
        __syncthreads();
    }
    if (i < N) rowStart[i] = tmp[tid] - v;
    if (tid == 0) blockSums[blockIdx.x] = tmp[1023];
}

__global__ void scan_sums(int* __restrict__ blockSums, int nb) {
    __shared__ int tmp[64];
    int tid = threadIdx.x;
    int v = (tid < nb) ? blockSums[tid] : 0;
    tmp[tid] = v;
    __syncthreads();
    for (int off = 1; off < 64; off <<= 1) {
        int t = (tid >= off) ? tmp[tid - off] : 0;
        __syncthreads();
        tmp[tid] += t;
        __syncthreads();
    }
    if (tid < nb) blockSums[tid] = tmp[tid] - v;
}

// finalize rowStart, init cursor, compute norms
__global__ void scan_add_norm(int* __restrict__ rowStart, const int* __restrict__ blockSums,
                              int* __restrict__ cursorPad,
                              const int* __restrict__ degOpad, const int* __restrict__ degIpad,
                              float* __restrict__ normO, float* __restrict__ normI,
                              int N, int E) {
    int i = blockIdx.x * blockDim.x + threadIdx.x;
    if (i < N) {
        int r = rowStart[i] + blockSums[i >> 10];
        rowStart[i] = r;
        cursorPad[i * PAD] = r;
        normO[i] = rsqrtf(fmaxf((float)degOpad[i * PAD], 1.0f));
        normI[i] = rsqrtf(fmaxf((float)degIpad[i * PAD], 1.0f));
    }
    if (i == N) rowStart[N] = E;
}

// ---------------- permute edges into dst-sorted order (padded cursor) ----------------
__global__ void permute_kernel(const int* __restrict__ src, const int* __restrict__ dst,
                               const float* __restrict__ efet, int* __restrict__ cursorPad,
                               int* __restrict__ srcSorted, __half* __restrict__ wSorted, int E) {
    int e = blockIdx.x * blockDim.x + threadIdx.x;
    if (e < E) {
        int d = dst[e];
        int p = atomicAdd(&cursorPad[d * PAD], 1);
        srcSorted[p] = src[e];
        wSorted[p] = __float2half(efet[e]);
    }
}

// ---------------- CSR gather-aggregation (unsliced), fused epilogue ----------------
template <int D, typename IT, typename OT>
__global__ void agg_kernel(const IT* __restrict__ in, OT* __restrict__ out,
                           const int* __restrict__ rowStart, const int* __restrict__ srcSorted,
                           const __half* __restrict__ wSorted,   // null -> 1
                           const float* __restrict__ srcScale,   // null -> 1
                           const float* __restrict__ dstScale,   // null -> skip scale+bias
                           const float* __restrict__ bias,
                           int N, int relu) {
    constexpr int TPN = D / 4;
    int gid = blockIdx.x * blockDim.x + threadIdx.x;
    int v = gid / TPN;
    int c4 = (gid % TPN) * 4;
    if (v >= N) return;
    int beg = rowStart[v], end = rowStart[v + 1];
    float ax = 0.f, ay = 0.f, az = 0.f, aw = 0.f;
    const IT* base = in + c4;

    int j = beg;
    for (; j + 4 <= end; j += 4) {
        int s0 = srcSorted[j + 0], s1 = srcSorted[j + 1];
        int s2 = srcSorted[j + 2], s3 = srcSorted[j + 3];
        float w0 = 1.f, w1 = 1.f, w2 = 1.f, w3 = 1.f;
        if (wSorted) {
            w0 = __half2float(wSorted[j + 0]); w1 = __half2float(wSorted[j + 1]);
            w2 = __half2float(wSorted[j + 2]); w3 = __half2float(wSorted[j + 3]);
        }
        if (srcScale) {
            w0 *= srcScale[s0]; w1 *= srcScale[s1];
            w2 *= srcScale[s2]; w3 *= srcScale[s3];
        }
        float4 x0 = ld4f(base + (size_t)s0 * D);
        float4 x1 = ld4f(base + (size_t)s1 * D);
        float4 x2 = ld4f(base + (size_t)s2 * D);
        float4 x3 = ld4f(base + (size_t)s3 * D);
        ax += x0.x * w0; ay += x0.y * w0; az += x0.z * w0; aw += x0.w * w0;
        ax += x1.x * w1; ay += x1.y * w1; az += x1.z * w1; aw += x1.w * w1;
        ax += x2.x * w2; ay += x2.y * w2; az += x2.z * w2; aw += x2.w * w2;
        ax += x3.x * w3; ay += x3.y * w3; az += x3.z * w3; aw += x3.w * w3;
    }
    for (; j < end; ++j) {
        int s = srcSorted[j];
        float w = 1.0f;
        if (wSorted) w = __half2float(wSorted[j]);
        if (srcScale) w *= srcScale[s];
        float4 val = ld4f(base + (size_t)s * D);
        ax += val.x * w; ay += val.y * w; az += val.z * w; aw += val.w * w;
    }
    if (dstScale) {
        float sc = dstScale[v];
        ax = ax * sc + bias[c4 + 0];
        ay = ay * sc + bias[c4 + 1];
        az = az * sc + bias[c4 + 2];
        aw = aw * sc + bias[c4 + 3];
    }
    if (relu) {
        ax = fmaxf(ax, 0.f); ay = fmaxf(ay, 0.f);
        az = fmaxf(az, 0.f); aw = fmaxf(aw, 0.f);
    }
    st4f(out + (size_t)v * D + c4, make_float4(ax, ay, az, aw));
}

// ---------------- column-sliced agg: 32-col slices for XCD-L2 locality ----------------
// slice = blockIdx.x % NS round-robins slices across XCDs; each XCD's working
// set becomes one 32-col slice (~3.2MB fp16) which fits per-XCD L2.
template <int D, int NS, typename IT, typename OT>
__global__ __launch_bounds__(256) void agg_sliced(
    const IT* __restrict__ in, OT* __restrict__ out,
    const int* __restrict__ rowStart, const int* __restrict__ srcSorted,
    const __half* __restrict__ wSorted,   // null -> 1
    const float* __restrict__ dstScale,   // null -> skip scale+bias
    const float* __restrict__ bias,
    int N, int relu)
{
    int slice = blockIdx.x % NS;
    int nb    = blockIdx.x / NS;
    int t = threadIdx.x;
    int v = nb * 32 + (t >> 3);
    if (v >= N) return;
    int c = slice * 32 + (t & 7) * 4;
    const IT* base = in + c;
    int beg = rowStart[v], end = rowStart[v + 1];
    float ax = 0.f, ay = 0.f, az = 0.f, aw = 0.f;

    int j = beg;
    for (; j + 4 <= end; j += 4) {
        int s0 = srcSorted[j + 0], s1 = srcSorted[j + 1];
        int s2 = srcSorted[j + 2], s3 = srcSorted[j + 3];
        float w0 = 1.f, w1 = 1.f, w2 = 1.f, w3 = 1.f;
        if (wSorted) {
            w0 = __half2float(wSorted[j + 0]); w1 = __half2float(wSorted[j + 1]);
            w2 = __half2float(wSorted[j + 2]); w3 = __half2float(wSorted[j + 3]);
        }
        float4 x0 = ld4f(base + (size_t)s0 * D);
        float4 x1 = ld4f(base + (size_t)s1 * D);
        float4 x2 = ld4f(base + (size_t)s2 * D);
        float4 x3 = ld4f(base + (size_t)s3 * D);
        ax += x0.x * w0; ay += x0.y * w0; az += x0.z * w0; aw += x0.w * w0;
        ax += x1.x * w1; ay += x1.y * w1; az += x1.z * w1; aw += x1.w * w1;
        ax += x2.x * w2; ay += x2.y * w2; az += x2.z * w2; aw += x2.w * w2;
        ax += x3.x * w3; ay += x3.y * w3; az += x3.z * w3; aw += x3.w * w3;
    }
    for (; j < end; ++j) {
        int s = srcSorted[j];
        float w = 1.0f;
        if (wSorted) w = __half2float(wSorted[j]);
        float4 val = ld4f(base + (size_t)s * D);
        ax += val.x * w; ay += val.y * w; az += val.z * w; aw += val.w * w;
    }
    if (dstScale) {
        float sc = dstScale[v];
        ax = ax * sc + bias[c + 0];
        ay = ay * sc + bias[c + 1];
        az = az * sc + bias[c + 2];
        aw = aw * sc + bias[c + 3];
    }
    if (relu) {
        ax = fmaxf(ax, 0.f); ay = fmaxf(ay, 0.f);
        az = fmaxf(az, 0.f); aw = fmaxf(aw, 0.f);
    }
    st4f(out + (size_t)v * D + c, make_float4(ax, ay, az, aw));
}

// ---------------- tiled register-blocked GEMM (A fp16/fp32, C fp16/fp32) ----------------
template <int KT, int RPT, int TN, typename AT, typename OT>
__global__ __launch_bounds__(256) void gemm_tiled(
    const AT* __restrict__ A, const float* __restrict__ W,
    const float* __restrict__ rowScaleIn,   // null -> 1
    const float* __restrict__ rowScaleOut,  // null -> no scale/bias
    const float* __restrict__ bias,
    OT* __restrict__ C, int N, int K1, int relu)
{
    constexpr int NC8 = TN / 8;
    constexpr int RT  = 256 / NC8;
    constexpr int TM  = RT * RPT;
    constexpr int AFPT = TM * KT / 256;
    constexpr int WF4  = KT * TN / 1024;
    static_assert(AFPT == 2 || AFPT == 8, "unexpected AFPT");

    __shared__ float Alds[KT][TM];
    __shared__ float Wlds[KT][TN];

    const int t    = threadIdx.x;
    const int cg   = t % NC8;
    const int rt   = t / NC8;
    const int c0   = cg * 8;
    const int row0 = blockIdx.x * TM;

    const int arow   = t % TM;
    const int akb    = (t / TM) * AFPT;
    const int arow_g = row0 + arow;
    float rsc = 1.0f;
    if (rowScaleIn && arow_g < N) rsc = rowScaleIn[arow_g];

    float acc[RPT][8];
#pragma unroll
    for (int r = 0; r < RPT; ++r)
#pragma unroll
        for (int j = 0; j < 8; ++j) acc[r][j] = 0.f;

    for (int k0 = 0; k0 < K1; k0 += KT) {
        float av[AFPT];
        if (arow_g < N) {
            const AT* ag = A + (size_t)arow_g * K1 + k0 + akb;
            if constexpr (AFPT == 8) ld8v(ag, av);
            else                     ld2v(ag, av);
        } else {
#pragma unroll
            for (int j = 0; j < AFPT; ++j) av[j] = 0.f;
        }
#pragma unroll
        for (int j = 0; j < AFPT; ++j)
            Alds[akb + j][arow] = av[j] * rsc;

        {
            const float4* wg = (const float4*)(W + (size_t)k0 * TN);
            float4* wl = (float4*)&Wlds[0][0];
#pragma unroll
            for (int j = 0; j < WF4; ++j) wl[j * 256 + t] = wg[j * 256 + t];
        }
        __syncthreads();

#pragma unroll
        for (int kk = 0; kk < KT; ++kk) {
            float a[RPT];
            if constexpr (RPT == 4) {
                float4 avv = *(const float4*)&Alds[kk][rt * 4];
                a[0] = avv.x; a[1] = avv.y; a[2] = avv.z; a[3] = avv.w;
            } else if constexpr (RPT == 2) {
                float2 avv = *(const float2*)&Alds[kk][rt * 2];
                a[0] = avv.x; a[1] = avv.y;
            } else {
                a[0] = Alds[kk][rt];
            }
            float4 w0 = *(const float4*)&Wlds[kk][c0];
            float4 w1 = *(const float4*)&Wlds[kk][c0 + 4];
#pragma unroll
            for (int r = 0; r < RPT; ++r) {
                acc[r][0] += a[r] * w0.x; acc[r][1] += a[r] * w0.y;
                acc[r][2] += a[r] * w0.z; acc[r][3] += a[r] * w0.w;
                acc[r][4] += a[r] * w1.x; acc[r][5] += a[r] * w1.y;
                acc[r][6] += a[r] * w1.z; acc[r][7] += a[r] * w1.w;
            }
        }
        __syncthreads();
    }

#pragma unroll
    for (int r = 0; r < RPT; ++r) {
        int row_g = row0 + rt * RPT + r;
        if (row_g >= N) continue;
        float f[8];
        if (rowScaleOut) {
            float sc = rowScaleOut[row_g];
#pragma unroll
            for (int j = 0; j < 8; ++j) f[j] = acc[r][j] * sc + bias[c0 + j];
        } else {
#pragma unroll
            for (int j = 0; j < 8; ++j) f[j] = acc[r][j];
        }
        if (relu) {
#pragma unroll
            for (int j = 0; j < 8; ++j) f[j] = fmaxf(f[j], 0.f);
        }
        st8f(C + (size_t)row_g * TN + c0, f);
    }
}

// ---------------- naive GEMM (K2=4 layer) ----------------
template <typename AT>
__global__ void gemm_naive(const AT* __restrict__ A, const float* __restrict__ W,
                           const float* __restrict__ rowScaleIn,
                           float* __restrict__ C, int N, int K1, int K2) {
    int gid = blockIdx.x * blockDim.x + threadIdx.x;
    int col = gid % K2;
    int row = gid / K2;
    if (row >= N) return;
    const AT* a = A + (size_t)row * K1;
    float acc = 0.0f;
    for (int k = 0; k < K1; ++k) acc += (float)a[k] * W[k * K2 + col];
    if (rowScaleIn) acc *= rowScaleIn[row];
    C[gid] = acc;
}

static inline int nblk(long n) { return (int)((n + BLOCK - 1) / BLOCK); }

extern "C" void kernel_launch(void* const* d_in, const int* in_sizes, int n_in,
                              void* d_out, int out_size, void* d_ws, size_t ws_size,
                              hipStream_t stream) {
    const float* x    = (const float*)d_in[0];
    const float* efet = (const float*)d_in[1];
    const int*   src  = (const int*)d_in[2];
    const int*   dst  = (const int*)d_in[3];
    const float* W1 = (const float*)d_in[4];  const float* b1 = (const float*)d_in[5];
    const float* W2 = (const float*)d_in[6];  const float* b2 = (const float*)d_in[7];
    const float* W3 = (const float*)d_in[8];  const float* b3 = (const float*)d_in[9];
    const float* W4 = (const float*)d_in[10]; const float* b4 = (const float*)d_in[11];
    const float* W5 = (const float*)d_in[12]; const float* b5 = (const float*)d_in[13];
    float* out = (float*)d_out;

    const int N = in_sizes[0] / 16;
    const int E = in_sizes[2];
    const int NB1024 = (N + 1023) / 1024;

    // ---- workspace layout (float units, 16B-aligned chunks) ----
    float* fws = (float*)d_ws;
    size_t o = 0;
    auto alloc = [&](size_t nf) { float* p = fws + o; o += (nf + 3) & ~(size_t)3; return p; };
    float*  normO     = alloc(N);
    float*  normI     = alloc(N);
    int*    rowStart  = (int*)alloc(N + 1);
    int*    blockSums = (int*)alloc(64);
    int*    srcSorted = (int*)alloc(E);
    int*    degOpad   = (int*)alloc((size_t)PAD * N);
    int*    degIpad   = (int*)alloc((size_t)PAD * N);
    int*    cursorPad = (int*)alloc((size_t)PAD * N);
    __half* wSortedH  = (__half*)alloc(E / 2 + 4);
    __half* bufA      = (__half*)alloc(128 * (size_t)N);   // 256N halves
    __half* bufB      = (__half*)alloc(128 * (size_t)N);   // 256N halves
    __half* bufC      = (__half*)alloc(64 * (size_t)N);    // 128N halves
    float*  t5f       = (float*)bufA;                      // reuse for layer-5 fp32 temp

    // ---- degrees + CSR build (degOpad/degIpad contiguous -> one memset) ----
    hipMemsetAsync(degOpad, 0, 2 * (size_t)PAD * N * sizeof(int), stream);
    deg_kernel<<<nblk(E), BLOCK, 0, stream>>>(src, dst, degOpad, degIpad, E);
    scan_local<<<NB1024, 1024, 0, stream>>>(degIpad, rowStart, blockSums, N);
    scan_sums<<<1, 64, 0, stream>>>(blockSums, NB1024);
    scan_add_norm<<<nblk(N + 1), BLOCK, 0, stream>>>(rowStart, blockSums, cursorPad,
                                                     degOpad, degIpad, normO, normI, N, E);
    permute_kernel<<<nblk(E), BLOCK, 0, stream>>>(src, dst, efet, cursorPad, srcSorted, wSortedH, E);

    const int NB32 = (N + 31) / 32;

    // ---- Layer 1: agg-first 16-dim -> fp16, GEMM 16->256 -> fp16, sliced ewa -> h1 fp16 ----
    agg_kernel<16, float, __half><<<nblk((long)N * 4), BLOCK, 0, stream>>>(
        x, bufC, rowStart, srcSorted, nullptr, normO, nullptr, nullptr, N, 0);
    gemm_tiled<16, 4, 256, __half, __half><<<(N + 31) / 32, 256, 0, stream>>>(
        bufC, W1, nullptr, normI, b1, bufA, N, 16, 1);
    agg_sliced<256, 8, __half, __half><<<8 * NB32, 256, 0, stream>>>(
        bufA, bufB, rowStart, srcSorted, wSortedH, nullptr, nullptr, N, 1);           // h1 = bufB

    // ---- Layer 2: GEMM 256->128 -> fp16, sliced gc-agg, sliced ewa ----
    gemm_tiled<32, 4, 128, __half, __half><<<(N + 63) / 64, 256, 0, stream>>>(
        bufB, W2, normO, nullptr, nullptr, bufA, N, 256, 0);
    agg_sliced<128, 4, __half, __half><<<4 * NB32, 256, 0, stream>>>(
        bufA, bufC, rowStart, srcSorted, nullptr, normI, b2, N, 1);
    agg_sliced<128, 4, __half, __half><<<4 * NB32, 256, 0, stream>>>(
        bufC, bufB, rowStart, srcSorted, wSortedH, nullptr, nullptr, N, 1);           // h2 = bufB

    // ---- Layer 3: GEMM 128->64 -> fp16, sliced gc-agg, sliced ewa ----
    gemm_tiled<32, 2, 64, __half, __half><<<(N + 63) / 64, 256, 0, stream>>>(
        bufB, W3, normO, nullptr, nullptr, bufA, N, 128, 0);
    agg_sliced<64, 2, __half, __half><<<2 * NB32, 256, 0, stream>>>(
        bufA, bufC, rowStart, srcSorted, nullptr, normI, b3, N, 1);
    agg_sliced<64, 2, __half, __half><<<2 * NB32, 256, 0, stream>>>(
        bufC, bufB, rowStart, srcSorted, wSortedH, nullptr, nullptr, N, 1);           // h3 = bufB

    // ---- Layer 4: GEMM 64->32 -> fp16, gc-agg -> h4 fp16 ----
    gemm_tiled<32, 1, 32, __half, __half><<<(N + 63) / 64, 256, 0, stream>>>(
        bufB, W4, normO, nullptr, nullptr, bufA, N, 64, 0);
    agg_kernel<32, __half, __half><<<nblk((long)N * 8), BLOCK, 0, stream>>>(
        bufA, bufB, rowStart, srcSorted, nullptr, nullptr, normI, b4, N, 1);          // h4 = bufB

    // ---- Layer 5: GEMM 32->4 (fp32 out), gc-agg -> out ----
    gemm_naive<__half><<<nblk((long)N * 4), BLOCK, 0, stream>>>(
        bufB, W5, normO, t5f, N, 32, 4);
    agg_kernel<4, float, float><<<nblk((long)N), BLOCK, 0, stream>>>(
        t5f, out, rowStart, srcSorted, nullptr, nullptr, normI, b5, N, 0);
}

// Round 8
// 527.380 us; speedup vs baseline: 1.3410x; 1.3410x over previous
//
#include <hip/hip_runtime.h>
#include <hip/hip_fp16.h>

#define BLOCK 256
#define PAD 16   // one counter per 64B cache line

// ---------------- typed vector load/store helpers ----------------
__device__ inline float4 ld4f(const float* p) { return *(const float4*)p; }
__device__ inline float4 ld4f(const __half* p) {
    uint2 u = *(const uint2*)p;
    __half2 a = *reinterpret_cast<__half2*>(&u.x);
    __half2 b = *reinterpret_cast<__half2*>(&u.y);
    float2 fa = __half22float2(a), fb = __half22float2(b);
    return make_float4(fa.x, fa.y, fb.x, fb.y);
}
__device__ inline void st4f(float* p, float4 v) { *(float4*)p = v; }
__device__ inline void st4f(__half* p, float4 v) {
    __half2 a = __floats2half2_rn(v.x, v.y);
    __half2 b = __floats2half2_rn(v.z, v.w);
    uint2 u;
    u.x = *reinterpret_cast<unsigned*>(&a);
    u.y = *reinterpret_cast<unsigned*>(&b);
    *(uint2*)p = u;
}
__device__ inline void st8f(float* p, const float f[8]) {
    *(float4*)p       = make_float4(f[0], f[1], f[2], f[3]);
    *(float4*)(p + 4) = make_float4(f[4], f[5], f[6], f[7]);
}
__device__ inline void st8f(__half* p, const float f[8]) {
    union { __half2 h[4]; float4 v; } u;
    u.h[0] = __floats2half2_rn(f[0], f[1]);
    u.h[1] = __floats2half2_rn(f[2], f[3]);
    u.h[2] = __floats2half2_rn(f[4], f[5]);
    u.h[3] = __floats2half2_rn(f[6], f[7]);
    *(float4*)p = u.v;
}
__device__ inline void ld2v(const float* p, float* f) {
    float2 v = *(const float2*)p; f[0] = v.x; f[1] = v.y;
}
__device__ inline void ld2v(const __half* p, float* f) {
    float2 v = __half22float2(*(const __half2*)p); f[0] = v.x; f[1] = v.y;
}
__device__ inline void ld8v(const float* p, float* f) {
    float4 a = *(const float4*)p, b = *(const float4*)(p + 4);
    f[0]=a.x; f[1]=a.y; f[2]=a.z; f[3]=a.w; f[4]=b.x; f[5]=b.y; f[6]=b.z; f[7]=b.w;
}
__device__ inline void ld8v(const __half* p, float* f) {
    float4 r = *(const float4*)p;
    const __half2* h = (const __half2*)&r;
#pragma unroll
    for (int j = 0; j < 4; ++j) {
        float2 fj = __half22float2(h[j]);
        f[2*j] = fj.x; f[2*j+1] = fj.y;
    }
}

// ---------------- degree (padded counters, int atomics) ----------------
__global__ void deg_kernel(const int* __restrict__ src, const int* __restrict__ dst,
                           int* __restrict__ degOpad, int* __restrict__ degIpad, int E) {
    int e = blockIdx.x * blockDim.x + threadIdx.x;
    if (e < E) {
        atomicAdd(&degOpad[src[e] * PAD], 1);
        atomicAdd(&degIpad[dst[e] * PAD], 1);
    }
}

// ---------------- hierarchical exclusive scan of degI (padded input) ----------------
__global__ void scan_local(const int* __restrict__ degIpad, int* __restrict__ rowStart,
                           int* __restrict__ blockSums, int N) {
    __shared__ int tmp[1024];
    int tid = threadIdx.x;
    int i = blockIdx.x * 1024 + tid;
    int v = (i < N) ? degIpad[i * PAD] : 0;
    tmp[tid] = v;
    __syncthreads();
    for (int off = 1; off < 1024; off <<= 1) {
        int t = (tid >= off) ? tmp[tid - off] : 0;
        __syncthreads();
        tmp[tid] += t;
        __syncthreads();
    }
    if (i < N) rowStart[i] = tmp[tid] - v;
    if (tid == 0) blockSums[blockIdx.x] = tmp[1023];
}

__global__ void scan_sums(int* __restrict__ blockSums, int nb) {
    __shared__ int tmp[64];
    int tid = threadIdx.x;
    int v = (tid < nb) ? blockSums[tid] : 0;
    tmp[tid] = v;
    __syncthreads();
    for (int off = 1; off < 64; off <<= 1) {
        int t = (tid >= off) ? tmp[tid - off] : 0;
        __syncthreads();
        tmp[tid] += t;
        __syncthreads();
    }
    if (tid < nb) blockSums[tid] = tmp[tid] - v;
}

// finalize rowStart, init cursor, compute norms
__global__ void scan_add_norm(int* __restrict__ rowStart, const int* __restrict__ blockSums,
                              int* __restrict__ cursorPad,
                              const int* __restrict__ degOpad, const int* __restrict__ degIpad,
                              float* __restrict__ normO, float* __restrict__ normI,
                              int N, int E) {
    int i = blockIdx.x * blockDim.x + threadIdx.x;
    if (i < N) {
        int r = rowStart[i] + blockSums[i >> 10];
        rowStart[i] = r;
        cursorPad[i * PAD] = r;
        normO[i] = rsqrtf(fmaxf((float)degOpad[i * PAD], 1.0f));
        normI[i] = rsqrtf(fmaxf((float)degIpad[i * PAD], 1.0f));
    }
    if (i == N) rowStart[N] = E;
}

// ---------------- permute edges into dst-sorted order (padded cursor) ----------------
__global__ void permute_kernel(const int* __restrict__ src, const int* __restrict__ dst,
                               const float* __restrict__ efet, int* __restrict__ cursorPad,
                               int* __restrict__ srcSorted, __half* __restrict__ wSorted, int E) {
    int e = blockIdx.x * blockDim.x + threadIdx.x;
    if (e < E) {
        int d = dst[e];
        int p = atomicAdd(&cursorPad[d * PAD], 1);
        srcSorted[p] = src[e];
        wSorted[p] = __float2half(efet[e]);
    }
}

// ---------------- CSR gather-aggregation, 4 cols/thread (small D) ----------------
template <int D, typename IT, typename OT>
__global__ void agg_kernel(const IT* __restrict__ in, OT* __restrict__ out,
                           const int* __restrict__ rowStart, const int* __restrict__ srcSorted,
                           const __half* __restrict__ wSorted,   // null -> 1
                           const float* __restrict__ srcScale,   // null -> 1
                           const float* __restrict__ dstScale,   // null -> skip scale+bias
                           const float* __restrict__ bias,
                           int N, int relu) {
    constexpr int TPN = D / 4;
    int gid = blockIdx.x * blockDim.x + threadIdx.x;
    int v = gid / TPN;
    int c4 = (gid % TPN) * 4;
    if (v >= N) return;
    int beg = rowStart[v], end = rowStart[v + 1];
    float ax = 0.f, ay = 0.f, az = 0.f, aw = 0.f;
    const IT* base = in + c4;

    int j = beg;
    for (; j + 4 <= end; j += 4) {
        int s0 = srcSorted[j + 0], s1 = srcSorted[j + 1];
        int s2 = srcSorted[j + 2], s3 = srcSorted[j + 3];
        float w0 = 1.f, w1 = 1.f, w2 = 1.f, w3 = 1.f;
        if (wSorted) {
            w0 = __half2float(wSorted[j + 0]); w1 = __half2float(wSorted[j + 1]);
            w2 = __half2float(wSorted[j + 2]); w3 = __half2float(wSorted[j + 3]);
        }
        if (srcScale) {
            w0 *= srcScale[s0]; w1 *= srcScale[s1];
            w2 *= srcScale[s2]; w3 *= srcScale[s3];
        }
        float4 x0 = ld4f(base + (size_t)s0 * D);
        float4 x1 = ld4f(base + (size_t)s1 * D);
        float4 x2 = ld4f(base + (size_t)s2 * D);
        float4 x3 = ld4f(base + (size_t)s3 * D);
        ax += x0.x * w0; ay += x0.y * w0; az += x0.z * w0; aw += x0.w * w0;
        ax += x1.x * w1; ay += x1.y * w1; az += x1.z * w1; aw += x1.w * w1;
        ax += x2.x * w2; ay += x2.y * w2; az += x2.z * w2; aw += x2.w * w2;
        ax += x3.x * w3; ay += x3.y * w3; az += x3.z * w3; aw += x3.w * w3;
    }
    for (; j < end; ++j) {
        int s = srcSorted[j];
        float w = 1.0f;
        if (wSorted) w = __half2float(wSorted[j]);
        if (srcScale) w *= srcScale[s];
        float4 val = ld4f(base + (size_t)s * D);
        ax += val.x * w; ay += val.y * w; az += val.z * w; aw += val.w * w;
    }
    if (dstScale) {
        float sc = dstScale[v];
        ax = ax * sc + bias[c4 + 0];
        ay = ay * sc + bias[c4 + 1];
        az = az * sc + bias[c4 + 2];
        aw = aw * sc + bias[c4 + 3];
    }
    if (relu) {
        ax = fmaxf(ax, 0.f); ay = fmaxf(ay, 0.f);
        az = fmaxf(az, 0.f); aw = fmaxf(aw, 0.f);
    }
    st4f(out + (size_t)v * D + c4, make_float4(ax, ay, az, aw));
}

// ---------------- CSR gather-aggregation, 8 cols/thread (D>=64, fp16) ----------------
// 16B gathers, 4 in flight; halves wave count and per-thread index overhead.
template <int D>
__global__ __launch_bounds__(256) void agg8_kernel(
    const __half* __restrict__ in, __half* __restrict__ out,
    const int* __restrict__ rowStart, const int* __restrict__ srcSorted,
    const __half* __restrict__ wSorted,   // null -> 1
    const float* __restrict__ dstScale,   // null -> skip scale+bias
    const float* __restrict__ bias,
    int N, int relu) {
    constexpr int TPN = D / 8;
    int gid = blockIdx.x * blockDim.x + threadIdx.x;
    int v = gid / TPN;
    int c8 = (gid % TPN) * 8;
    if (v >= N) return;
    int beg = rowStart[v], end = rowStart[v + 1];
    float a[8];
#pragma unroll
    for (int k = 0; k < 8; ++k) a[k] = 0.f;
    const __half* base = in + c8;

    int j = beg;
    for (; j + 4 <= end; j += 4) {
        int s0 = srcSorted[j + 0], s1 = srcSorted[j + 1];
        int s2 = srcSorted[j + 2], s3 = srcSorted[j + 3];
        float w0 = 1.f, w1 = 1.f, w2 = 1.f, w3 = 1.f;
        if (wSorted) {
            w0 = __half2float(wSorted[j + 0]); w1 = __half2float(wSorted[j + 1]);
            w2 = __half2float(wSorted[j + 2]); w3 = __half2float(wSorted[j + 3]);
        }
        float x0[8], x1[8], x2[8], x3[8];
        ld8v(base + (size_t)s0 * D, x0);
        ld8v(base + (size_t)s1 * D, x1);
        ld8v(base + (size_t)s2 * D, x2);
        ld8v(base + (size_t)s3 * D, x3);
#pragma unroll
        for (int k = 0; k < 8; ++k)
            a[k] += x0[k] * w0 + x1[k] * w1 + x2[k] * w2 + x3[k] * w3;
    }
    for (; j < end; ++j) {
        int s = srcSorted[j];
        float w = 1.0f;
        if (wSorted) w = __half2float(wSorted[j]);
        float xv[8];
        ld8v(base + (size_t)s * D, xv);
#pragma unroll
        for (int k = 0; k < 8; ++k) a[k] += xv[k] * w;
    }
    if (dstScale) {
        float sc = dstScale[v];
#pragma unroll
        for (int k = 0; k < 8; ++k) a[k] = a[k] * sc + bias[c8 + k];
    }
    if (relu) {
#pragma unroll
        for (int k = 0; k < 8; ++k) a[k] = fmaxf(a[k], 0.f);
    }
    st8f(out + (size_t)v * D + c8, a);
}

// ---------------- tiled register-blocked GEMM (A fp16/fp32, C fp16/fp32) ----------------
template <int KT, int RPT, int TN, typename AT, typename OT>
__global__ __launch_bounds__(256) void gemm_tiled(
    const AT* __restrict__ A, const float* __restrict__ W,
    const float* __restrict__ rowScaleIn,   // null -> 1
    const float* __restrict__ rowScaleOut,  // null -> no scale/bias
    const float* __restrict__ bias,
    OT* __restrict__ C, int N, int K1, int relu)
{
    constexpr int NC8 = TN / 8;
    constexpr int RT  = 256 / NC8;
    constexpr int TM  = RT * RPT;
    constexpr int AFPT = TM * KT / 256;
    constexpr int WF4  = KT * TN / 1024;
    static_assert(AFPT == 2 || AFPT == 8, "unexpected AFPT");

    __shared__ float Alds[KT][TM];
    __shared__ float Wlds[KT][TN];

    const int t    = threadIdx.x;
    const int cg   = t % NC8;
    const int rt   = t / NC8;
    const int c0   = cg * 8;
    const int row0 = blockIdx.x * TM;

    const int arow   = t % TM;
    const int akb    = (t / TM) * AFPT;
    const int arow_g = row0 + arow;
    float rsc = 1.0f;
    if (rowScaleIn && arow_g < N) rsc = rowScaleIn[arow_g];

    float acc[RPT][8];
#pragma unroll
    for (int r = 0; r < RPT; ++r)
#pragma unroll
        for (int j = 0; j < 8; ++j) acc[r][j] = 0.f;

    for (int k0 = 0; k0 < K1; k0 += KT) {
        float av[AFPT];
        if (arow_g < N) {
            const AT* ag = A + (size_t)arow_g * K1 + k0 + akb;
            if constexpr (AFPT == 8) ld8v(ag, av);
            else                     ld2v(ag, av);
        } else {
#pragma unroll
            for (int j = 0; j < AFPT; ++j) av[j] = 0.f;
        }
#pragma unroll
        for (int j = 0; j < AFPT; ++j)
            Alds[akb + j][arow] = av[j] * rsc;

        {
            const float4* wg = (const float4*)(W + (size_t)k0 * TN);
            float4* wl = (float4*)&Wlds[0][0];
#pragma unroll
            for (int j = 0; j < WF4; ++j) wl[j * 256 + t] = wg[j * 256 + t];
        }
        __syncthreads();

#pragma unroll
        for (int kk = 0; kk < KT; ++kk) {
            float a[RPT];
            if constexpr (RPT == 4) {
                float4 avv = *(const float4*)&Alds[kk][rt * 4];
                a[0] = avv.x; a[1] = avv.y; a[2] = avv.z; a[3] = avv.w;
            } else if constexpr (RPT == 2) {
                float2 avv = *(const float2*)&Alds[kk][rt * 2];
                a[0] = avv.x; a[1] = avv.y;
            } else {
                a[0] = Alds[kk][rt];
            }
            float4 w0 = *(const float4*)&Wlds[kk][c0];
            float4 w1 = *(const float4*)&Wlds[kk][c0 + 4];
#pragma unroll
            for (int r = 0; r < RPT; ++r) {
                acc[r][0] += a[r] * w0.x; acc[r][1] += a[r] * w0.y;
                acc[r][2] += a[r] * w0.z; acc[r][3] += a[r] * w0.w;
                acc[r][4] += a[r] * w1.x; acc[r][5] += a[r] * w1.y;
                acc[r][6] += a[r] * w1.z; acc[r][7] += a[r] * w1.w;
            }
        }
        __syncthreads();
    }

#pragma unroll
    for (int r = 0; r < RPT; ++r) {
        int row_g = row0 + rt * RPT + r;
        if (row_g >= N) continue;
        float f[8];
        if (rowScaleOut) {
            float sc = rowScaleOut[row_g];
#pragma unroll
            for (int j = 0; j < 8; ++j) f[j] = acc[r][j] * sc + bias[c0 + j];
        } else {
#pragma unroll
            for (int j = 0; j < 8; ++j) f[j] = acc[r][j];
        }
        if (relu) {
#pragma unroll
            for (int j = 0; j < 8; ++j) f[j] = fmaxf(f[j], 0.f);
        }
        st8f(C + (size_t)row_g * TN + c0, f);
    }
}

// ---------------- naive GEMM (K2=4 layer) ----------------
template <typename AT>
__global__ void gemm_naive(const AT* __restrict__ A, const float* __restrict__ W,
                           const float* __restrict__ rowScaleIn,
                           float* __restrict__ C, int N, int K1, int K2) {
    int gid = blockIdx.x * blockDim.x + threadIdx.x;
    int col = gid % K2;
    int row = gid / K2;
    if (row >= N) return;
    const AT* a = A + (size_t)row * K1;
    float acc = 0.0f;
    for (int k = 0; k < K1; ++k) acc += (float)a[k] * W[k * K2 + col];
    if (rowScaleIn) acc *= rowScaleIn[row];
    C[gid] = acc;
}

static inline int nblk(long n) { return (int)((n + BLOCK - 1) / BLOCK); }

extern "C" void kernel_launch(void* const* d_in, const int* in_sizes, int n_in,
                              void* d_out, int out_size, void* d_ws, size_t ws_size,
                              hipStream_t stream) {
    const float* x    = (const float*)d_in[0];
    const float* efet = (const float*)d_in[1];
    const int*   src  = (const int*)d_in[2];
    const int*   dst  = (const int*)d_in[3];
    const float* W1 = (const float*)d_in[4];  const float* b1 = (const float*)d_in[5];
    const float* W2 = (const float*)d_in[6];  const float* b2 = (const float*)d_in[7];
    const float* W3 = (const float*)d_in[8];  const float* b3 = (const float*)d_in[9];
    const float* W4 = (const float*)d_in[10]; const float* b4 = (const float*)d_in[11];
    const float* W5 = (const float*)d_in[12]; const float* b5 = (const float*)d_in[13];
    float* out = (float*)d_out;

    const int N = in_sizes[0] / 16;
    const int E = in_sizes[2];
    const int NB1024 = (N + 1023) / 1024;

    // ---- workspace layout (float units, 16B-aligned chunks) ----
    float* fws = (float*)d_ws;
    size_t o = 0;
    auto alloc = [&](size_t nf) { float* p = fws + o; o += (nf + 3) & ~(size_t)3; return p; };
    float*  normO     = alloc(N);
    float*  normI     = alloc(N);
    int*    rowStart  = (int*)alloc(N + 1);
    int*    blockSums = (int*)alloc(64);
    int*    srcSorted = (int*)alloc(E);
    int*    degOpad   = (int*)alloc((size_t)PAD * N);
    int*    degIpad   = (int*)alloc((size_t)PAD * N);
    int*    cursorPad = (int*)alloc((size_t)PAD * N);
    __half* wSortedH  = (__half*)alloc(E / 2 + 4);
    __half* bufA      = (__half*)alloc(128 * (size_t)N);   // 256N halves
    __half* bufB      = (__half*)alloc(128 * (size_t)N);   // 256N halves
    __half* bufC      = (__half*)alloc(64 * (size_t)N);    // 128N halves
    float*  t5f       = (float*)bufA;                      // reuse for layer-5 fp32 temp

    // ---- degrees + CSR build ----
    hipMemsetAsync(degOpad, 0, 2 * (size_t)PAD * N * sizeof(int), stream);
    deg_kernel<<<nblk(E), BLOCK, 0, stream>>>(src, dst, degOpad, degIpad, E);
    scan_local<<<NB1024, 1024, 0, stream>>>(degIpad, rowStart, blockSums, N);
    scan_sums<<<1, 64, 0, stream>>>(blockSums, NB1024);
    scan_add_norm<<<nblk(N + 1), BLOCK, 0, stream>>>(rowStart, blockSums, cursorPad,
                                                     degOpad, degIpad, normO, normI, N, E);
    permute_kernel<<<nblk(E), BLOCK, 0, stream>>>(src, dst, efet, cursorPad, srcSorted, wSortedH, E);

    // ---- Layer 1: agg-first 16-dim -> fp16, GEMM 16->256 -> fp16, ewa8 -> h1 fp16 ----
    agg_kernel<16, float, __half><<<nblk((long)N * 4), BLOCK, 0, stream>>>(
        x, bufC, rowStart, srcSorted, nullptr, normO, nullptr, nullptr, N, 0);
    gemm_tiled<16, 4, 256, __half, __half><<<(N + 31) / 32, 256, 0, stream>>>(
        bufC, W1, nullptr, normI, b1, bufA, N, 16, 1);
    agg8_kernel<256><<<nblk((long)N * 32), BLOCK, 0, stream>>>(
        bufA, bufB, rowStart, srcSorted, wSortedH, nullptr, nullptr, N, 1);           // h1 = bufB

    // ---- Layer 2: GEMM 256->128 -> fp16, gc-agg8, ewa8 ----
    gemm_tiled<32, 4, 128, __half, __half><<<(N + 63) / 64, 256, 0, stream>>>(
        bufB, W2, normO, nullptr, nullptr, bufA, N, 256, 0);
    agg8_kernel<128><<<nblk((long)N * 16), BLOCK, 0, stream>>>(
        bufA, bufC, rowStart, srcSorted, nullptr, normI, b2, N, 1);
    agg8_kernel<128><<<nblk((long)N * 16), BLOCK, 0, stream>>>(
        bufC, bufB, rowStart, srcSorted, wSortedH, nullptr, nullptr, N, 1);           // h2 = bufB

    // ---- Layer 3: GEMM 128->64 -> fp16, gc-agg8, ewa8 ----
    gemm_tiled<32, 2, 64, __half, __half><<<(N + 63) / 64, 256, 0, stream>>>(
        bufB, W3, normO, nullptr, nullptr, bufA, N, 128, 0);
    agg8_kernel<64><<<nblk((long)N * 8), BLOCK, 0, stream>>>(
        bufA, bufC, rowStart, srcSorted, nullptr, normI, b3, N, 1);
    agg8_kernel<64><<<nblk((long)N * 8), BLOCK, 0, stream>>>(
        bufC, bufB, rowStart, srcSorted, wSortedH, nullptr, nullptr, N, 1);           // h3 = bufB

    // ---- Layer 4: GEMM 64->32 -> fp16, gc-agg -> h4 fp16 ----
    gemm_tiled<32, 1, 32, __half, __half><<<(N + 63) / 64, 256, 0, stream>>>(
        bufB, W4, normO, nullptr, nullptr, bufA, N, 64, 0);
    agg_kernel<32, __half, __half><<<nblk((long)N * 8), BLOCK, 0, stream>>>(
        bufA, bufB, rowStart, srcSorted, nullptr, nullptr, normI, b4, N, 1);          // h4 = bufB

    // ---- Layer 5: GEMM 32->4 (fp32 out), gc-agg -> out ----
    gemm_naive<__half><<<nblk((long)N * 4), BLOCK, 0, stream>>>(
        bufB, W5, normO, t5f, N, 32, 4);
    agg_kernel<4, float, float><<<nblk((long)N), BLOCK, 0, stream>>>(
        t5f, out, rowStart, srcSorted, nullptr, nullptr, normI, b5, N, 0);
}